// Round 8
// baseline (279.066 us; speedup 1.0000x reference)
//
#include <hip/hip_runtime.h>
#include <hip/hip_fp16.h>

constexpr int N_NODES = 50000;
constexpr int N_EDGES = 640000;

constexpr int NBLK  = 256;                    // edge-chunk blocks
constexpr int EPB   = N_EDGES / NBLK;         // 2500 (exact)
constexpr int NBUCK = (N_NODES + 255) / 256;  // 196 buckets of 256 dst each
constexpr int GBM   = (N_NODES + 63) / 64;    // mfma-gemm blocks (64 rows each)

typedef _Float16 half8  __attribute__((ext_vector_type(8)));
typedef _Float16 half4v __attribute__((ext_vector_type(4)));
typedef float    floatx4 __attribute__((ext_vector_type(4)));

// ---------------- W -> W^T fp16 conversion (one-time, tiny) ----------------

__global__ void wconv_k(const float* __restrict__ W1, const float* __restrict__ W2,
                        const float* __restrict__ W3, _Float16* __restrict__ Wt1,
                        _Float16* __restrict__ Wt2, _Float16* __restrict__ Wt3) {
    int i = blockIdx.x * 256 + threadIdx.x;
    if (i < 16384) {
        int n = i >> 7, k = i & 127;
        Wt1[n * 128 + k] = (_Float16)W1[k * 128 + n];
    } else if (i < 32768) {
        int j = i - 16384; int n = j >> 7, k = j & 127;
        Wt2[n * 128 + k] = (_Float16)W2[k * 128 + n];
    } else if (i < 32768 + 6144) {
        int j = i - 32768; int n = j >> 7, k = j & 127;
        Wt3[n * 128 + k] = (_Float16)((n < 40) ? W3[k * 40 + n] : 0.f);
    }
}

// ---------------- MFMA GEMM: H[N,F_OUT] = X[N,128] @ W, fp16 in/out, fp32 acc ----------------

template<typename TIN, int F_OUT, int NT, bool FUSE_HIST>
__global__ __launch_bounds__(256) void gemm_mfma_k(const TIN* __restrict__ X,
        const _Float16* __restrict__ Wt, __half* __restrict__ H,
        const int* __restrict__ dst, int* __restrict__ gh) {
    if constexpr (FUSE_HIST) {
        if (blockIdx.x < NBLK) {
            __shared__ int lh[256];
            int t = threadIdx.x, b = blockIdx.x;
            lh[t] = 0;
            __syncthreads();
            int e0 = b * EPB;
            for (int j = t; j < EPB; j += 256)
                atomicAdd(&lh[dst[e0 + j] >> 8], 1);
            __syncthreads();
            if (t < NBUCK) gh[b * NBUCK + t] = lh[t];
            return;
        }
    }
    int bid = FUSE_HIST ? (int)blockIdx.x - NBLK : (int)blockIdx.x;

    __shared__ _Float16 Xs[64 * 136];      // 64 rows, stride 136 (16B-aligned pad)
    int tid = threadIdx.x;
    int row0 = bid * 64;

    if constexpr (sizeof(TIN) == 4) {      // fp32 input -> convert
        for (int idx = tid; idx < 2048; idx += 256) {
            int r = idx >> 5, c4 = idx & 31;
            float4 v = {0.f, 0.f, 0.f, 0.f};
            if (row0 + r < N_NODES)
                v = *(const float4*)((const float*)X + (size_t)(row0 + r) * 128 + c4 * 4);
            half4v h;
            h[0] = (_Float16)v.x; h[1] = (_Float16)v.y;
            h[2] = (_Float16)v.z; h[3] = (_Float16)v.w;
            *(half4v*)&Xs[r * 136 + c4 * 4] = h;
        }
    } else {                               // fp16 input -> raw copy
        for (int idx = tid; idx < 1024; idx += 256) {
            int r = idx >> 4, c8 = idx & 15;
            int4 v = {0, 0, 0, 0};
            if (row0 + r < N_NODES)
                v = *(const int4*)((const __half*)X + (size_t)(row0 + r) * 128 + c8 * 8);
            *(int4*)&Xs[r * 136 + c8 * 8] = v;
        }
    }
    __syncthreads();

    int lane = tid & 63;
    int wv   = tid >> 6;                   // wave 0..3 -> rows wv*16..+15
    int m    = lane & 15;
    int q    = lane >> 4;

    half8 af[4];
    #pragma unroll
    for (int kt = 0; kt < 4; kt++)
        af[kt] = *(const half8*)&Xs[(wv * 16 + m) * 136 + kt * 32 + q * 8];

    floatx4 acc[NT];
    #pragma unroll
    for (int nt = 0; nt < NT; nt++) { acc[nt][0] = 0.f; acc[nt][1] = 0.f; acc[nt][2] = 0.f; acc[nt][3] = 0.f; }

    #pragma unroll
    for (int nt = 0; nt < NT; nt++) {
        const _Float16* wp = Wt + (size_t)(nt * 16 + m) * 128 + q * 8;
        half8 b0 = *(const half8*)(wp);
        half8 b1 = *(const half8*)(wp + 32);
        half8 b2 = *(const half8*)(wp + 64);
        half8 b3 = *(const half8*)(wp + 96);
        acc[nt] = __builtin_amdgcn_mfma_f32_16x16x32_f16(af[0], b0, acc[nt], 0, 0, 0);
        acc[nt] = __builtin_amdgcn_mfma_f32_16x16x32_f16(af[1], b1, acc[nt], 0, 0, 0);
        acc[nt] = __builtin_amdgcn_mfma_f32_16x16x32_f16(af[2], b2, acc[nt], 0, 0, 0);
        acc[nt] = __builtin_amdgcn_mfma_f32_16x16x32_f16(af[3], b3, acc[nt], 0, 0, 0);
    }

    // C -> own wave's LDS region (rows wv*16..+15 only; no cross-wave hazard)
    #pragma unroll
    for (int nt = 0; nt < NT; nt++) {
        #pragma unroll
        for (int r = 0; r < 4; r++)
            Xs[(wv * 16 + q * 4 + r) * 136 + nt * 16 + m] = (_Float16)acc[nt][r];
    }

    // coalesced copy-out of own region
    if constexpr (F_OUT == 128) {
        for (int g = lane; g < 256; g += 64) {
            int r = g >> 4, c8 = g & 15;
            int row = row0 + wv * 16 + r;
            if (row < N_NODES)
                *(int4*)((__half*)H + (size_t)row * 128 + c8 * 8) =
                    *(const int4*)&Xs[(wv * 16 + r) * 136 + c8 * 8];
        }
    } else {                               // F_OUT = 40: 5 int4 per row
        for (int g = lane; g < 80; g += 64) {
            int r = g / 5, seg = g - r * 5;
            int row = row0 + wv * 16 + r;
            if (row < N_NODES)
                *(int4*)((__half*)H + (size_t)row * 40 + seg * 8) =
                    *(const int4*)&Xs[(wv * 16 + r) * 136 + seg * 8];
        }
    }
}

// ---------------- sort scans ----------------

__global__ __launch_bounds__(256) void scan1_k(int* __restrict__ gh, int* __restrict__ total) {
    __shared__ int s[256];
    int t = threadIdx.x, b = blockIdx.x;
    int v = gh[t * NBUCK + b];
    s[t] = v;
    __syncthreads();
    int x = v;
    for (int off = 1; off < 256; off <<= 1) {
        int u = (t >= off) ? s[t - off] : 0;
        __syncthreads();
        x += u; s[t] = x;
        __syncthreads();
    }
    gh[t * NBUCK + b] = x - v;            // exclusive within bucket
    if (t == 255) total[b] = x;
}

__global__ __launch_bounds__(256) void scan2_k(const int* __restrict__ total,
                                               int* __restrict__ bbase) {
    __shared__ int s[256];
    int t = threadIdx.x;
    int v = (t < NBUCK) ? total[t] : 0;
    s[t] = v;
    __syncthreads();
    int x = v;
    for (int off = 1; off < 256; off <<= 1) {
        int u = (t >= off) ? s[t - off] : 0;
        __syncthreads();
        x += u; s[t] = x;
        __syncthreads();
    }
    if (t <= NBUCK) bbase[t] = x - v;
}

// ---------------- bucket scatter (LDS cursors, no global atomics) ----------------

__global__ __launch_bounds__(256) void bucket_k(const int* __restrict__ src,
        const int* __restrict__ dst, const float* __restrict__ ew,
        const int* __restrict__ gh, const int* __restrict__ bbase,
        int2* __restrict__ bkt) {
    __shared__ int cur[256];
    int t = threadIdx.x, b = blockIdx.x;
    if (t < NBUCK) cur[t] = bbase[t] + gh[b * NBUCK + t];
    __syncthreads();
    int e0 = b * EPB;
    for (int j = t; j < EPB; j += 256) {
        int d = dst[e0 + j];
        int pos = atomicAdd(&cur[d >> 8], 1);
        bkt[pos] = make_int2(src[e0 + j] | (d << 16), __float_as_int(ew[e0 + j]));
    }
}

// ---------------- finalize: per-bucket dst sort + rowptr + dinv ----------------

__global__ __launch_bounds__(256) void final_k(const int2* __restrict__ bkt,
        const int* __restrict__ bbase, int2* __restrict__ ev,
        int* __restrict__ rowptr, float* __restrict__ dinv) {
    __shared__ int   cnt[256];
    __shared__ float wsum[256];
    __shared__ int   s[256];
    int t = threadIdx.x, b = blockIdx.x;
    int base = bbase[b], cntb = bbase[b + 1] - base;
    cnt[t] = 0; wsum[t] = 0.f;
    __syncthreads();
    for (int j = t; j < cntb; j += 256) {
        int2 r = bkt[base + j];
        int bin = (r.x >> 16) & 255;
        atomicAdd(&cnt[bin], 1);
        atomicAdd(&wsum[bin], __int_as_float(r.y));
    }
    __syncthreads();
    int v = cnt[t];
    s[t] = v;
    __syncthreads();
    int x = v;
    for (int off = 1; off < 256; off <<= 1) {
        int u = (t >= off) ? s[t - off] : 0;
        __syncthreads();
        x += u; s[t] = x;
        __syncthreads();
    }
    int off_t = x - v;
    int nd = b * 256 + t;
    if (nd < N_NODES) {
        rowptr[nd] = base + off_t;
        dinv[nd] = rsqrtf(1.0f + wsum[t]);
    }
    if (b == 0 && t == 0) rowptr[N_NODES] = N_EDGES;
    s[t] = off_t;
    __syncthreads();
    for (int j = t; j < cntb; j += 256) {
        int2 r = bkt[base + j];
        int bin = (r.x >> 16) & 255;
        int p = atomicAdd(&s[bin], 1);
        ev[base + p] = make_int2(r.x & 0xFFFF, r.y);
    }
}

// ---------------- norm pack: evc[e] = src16 | half(dinv_s*ew*dinv_d)<<16 ----------------

__global__ void norm_k(const int2* __restrict__ ev, const int* __restrict__ rowptr,
                       const float* __restrict__ dinv, int* __restrict__ evc) {
    int i = blockIdx.x * 256 + threadIdx.x;
    if (i >= N_NODES) return;
    int e0 = rowptr[i], e1 = rowptr[i + 1];
    float di = dinv[i];
    for (int e = e0; e < e1; e++) {
        int2 p = ev[e];
        float nrm = __int_as_float(p.y) * dinv[p.x] * di;
        unsigned short hb = __half_as_ushort(__float2half_rn(nrm));
        evc[e] = (p.x & 0xFFFF) | ((int)hb << 16);
    }
}

// ---------------- Aggregation, 128 features, feature-sliced ----------------
// out_i = relu( sum_e norm_e*h[src] + dinv_i^2*h_i + bias )
// slice = blockIdx&3 (XCD L2 affinity): 32 features; wave = 4 node-groups x 16 lanes (half2).

__global__ __launch_bounds__(256) void agg128s_k(const __half* __restrict__ H,
        const int* __restrict__ evc, const int* __restrict__ rowptr,
        const float* __restrict__ dinv, const float* __restrict__ bias,
        __half* __restrict__ out) {
    int slice = blockIdx.x & 3;
    int chunk = blockIdx.x >> 2;
    int tid  = threadIdx.x;
    int lane = tid & 63;
    int wv   = tid >> 6;
    int g    = lane >> 4;          // node group 0..3
    int f    = lane & 15;          // half2 column within slice
    int node = chunk * 16 + wv * 4 + g;
    if (node >= N_NODES) return;
    const __half2* __restrict__ H2 = (const __half2*)H;
    int col = slice * 16 + f;      // half2 column 0..63
    float di = dinv[node];
    float sn = di * di;
    float2 hs = __half22float2(H2[(size_t)node * 64 + col]);
    float ax = sn * hs.x, ay = sn * hs.y;
    int e0 = rowptr[node], e1 = rowptr[node + 1];
    int e = e0;
    for (; e + 4 <= e1; e += 4) {
        int v0 = evc[e + 0];
        int v1 = evc[e + 1];
        int v2 = evc[e + 2];
        int v3 = evc[e + 3];
        float2 g0 = __half22float2(H2[(size_t)(v0 & 0xFFFF) * 64 + col]);
        float2 g1 = __half22float2(H2[(size_t)(v1 & 0xFFFF) * 64 + col]);
        float2 g2 = __half22float2(H2[(size_t)(v2 & 0xFFFF) * 64 + col]);
        float2 g3 = __half22float2(H2[(size_t)(v3 & 0xFFFF) * 64 + col]);
        float w0 = __half2float(__ushort_as_half((unsigned short)((unsigned)v0 >> 16)));
        float w1 = __half2float(__ushort_as_half((unsigned short)((unsigned)v1 >> 16)));
        float w2 = __half2float(__ushort_as_half((unsigned short)((unsigned)v2 >> 16)));
        float w3 = __half2float(__ushort_as_half((unsigned short)((unsigned)v3 >> 16)));
        ax = fmaf(w0, g0.x, ax); ay = fmaf(w0, g0.y, ay);
        ax = fmaf(w1, g1.x, ax); ay = fmaf(w1, g1.y, ay);
        ax = fmaf(w2, g2.x, ax); ay = fmaf(w2, g2.y, ay);
        ax = fmaf(w3, g3.x, ax); ay = fmaf(w3, g3.y, ay);
    }
    for (; e < e1; e++) {
        int v = evc[e];
        float2 gv = __half22float2(H2[(size_t)(v & 0xFFFF) * 64 + col]);
        float w = __half2float(__ushort_as_half((unsigned short)((unsigned)v >> 16)));
        ax = fmaf(w, gv.x, ax);
        ay = fmaf(w, gv.y, ay);
    }
    float2 b = *(const float2*)&bias[slice * 32 + 2 * f];
    ax = fmaxf(ax + b.x, 0.f);
    ay = fmaxf(ay + b.y, 0.f);
    ((__half2*)out)[(size_t)node * 64 + col] = __float22half2_rn(make_float2(ax, ay));
}

// ---------------- Aggregation, 40 features -> fp32 out with bias ----------------

__global__ __launch_bounds__(256) void agg40_k(const __half* __restrict__ Y,
        const int* __restrict__ evc, const int* __restrict__ rowptr,
        const float* __restrict__ dinv, const float* __restrict__ bias,
        float* __restrict__ out) {
    int lane = threadIdx.x & 63;
    int node = __builtin_amdgcn_readfirstlane(blockIdx.x * 4 + (threadIdx.x >> 6));
    if (node >= N_NODES) return;
    const __half2* __restrict__ Y2 = (const __half2*)Y;
    int f = (lane < 20) ? lane : 0;            // half2 column
    float di = dinv[node];
    float sn = di * di;
    float2 ys = __half22float2(Y2[(size_t)node * 20 + f]);
    float ax = sn * ys.x, ay = sn * ys.y;
    int e0 = rowptr[node], e1 = rowptr[node + 1];
    int e = e0;
    for (; e + 4 <= e1; e += 4) {
        int v0 = evc[e + 0];
        int v1 = evc[e + 1];
        int v2 = evc[e + 2];
        int v3 = evc[e + 3];
        float2 g0 = __half22float2(Y2[(size_t)(v0 & 0xFFFF) * 20 + f]);
        float2 g1 = __half22float2(Y2[(size_t)(v1 & 0xFFFF) * 20 + f]);
        float2 g2 = __half22float2(Y2[(size_t)(v2 & 0xFFFF) * 20 + f]);
        float2 g3 = __half22float2(Y2[(size_t)(v3 & 0xFFFF) * 20 + f]);
        float w0 = __half2float(__ushort_as_half((unsigned short)((unsigned)v0 >> 16)));
        float w1 = __half2float(__ushort_as_half((unsigned short)((unsigned)v1 >> 16)));
        float w2 = __half2float(__ushort_as_half((unsigned short)((unsigned)v2 >> 16)));
        float w3 = __half2float(__ushort_as_half((unsigned short)((unsigned)v3 >> 16)));
        ax = fmaf(w0, g0.x, ax); ay = fmaf(w0, g0.y, ay);
        ax = fmaf(w1, g1.x, ax); ay = fmaf(w1, g1.y, ay);
        ax = fmaf(w2, g2.x, ax); ay = fmaf(w2, g2.y, ay);
        ax = fmaf(w3, g3.x, ax); ay = fmaf(w3, g3.y, ay);
    }
    for (; e < e1; e++) {
        int v = evc[e];
        float2 gv = __half22float2(Y2[(size_t)(v & 0xFFFF) * 20 + f]);
        float w = __half2float(__ushort_as_half((unsigned short)((unsigned)v >> 16)));
        ax = fmaf(w, gv.x, ax);
        ay = fmaf(w, gv.y, ay);
    }
    if (lane < 20) {
        float2 b = *(const float2*)&bias[2 * lane];
        float2 o;
        o.x = ax + b.x;
        o.y = ay + b.y;
        *(float2*)&out[(size_t)node * 40 + 2 * lane] = o;
    }
}

// ---------------- launch ----------------

extern "C" void kernel_launch(void* const* d_in, const int* in_sizes, int n_in,
                              void* d_out, int out_size, void* d_ws, size_t ws_size,
                              hipStream_t stream) {
    const float* x  = (const float*)d_in[0];
    const int*   ei = (const int*)d_in[1];
    const int*   src = ei;
    const int*   dst = ei + N_EDGES;
    const float* ew = (const float*)d_in[2];
    const float* W1 = (const float*)d_in[3];
    const float* b1 = (const float*)d_in[4];
    const float* W2 = (const float*)d_in[5];
    const float* b2 = (const float*)d_in[6];
    const float* W3 = (const float*)d_in[7];
    const float* b3 = (const float*)d_in[8];
    float* out = (float*)d_out;

    char* w = (char*)d_ws;
    auto alloc = [&](size_t bytes) {
        char* p = w;
        w += (bytes + 255) & ~(size_t)255;
        return p;
    };
    float*     dinv   = (float*)    alloc((size_t)N_NODES * 4);
    int*       rowptr = (int*)      alloc((size_t)(N_NODES + 1) * 4);
    int*       gh     = (int*)      alloc((size_t)NBLK * NBUCK * 4);
    int*       total  = (int*)      alloc((size_t)NBUCK * 4);
    int*       bbase  = (int*)      alloc((size_t)(NBUCK + 1) * 4);
    int2*      bkt    = (int2*)     alloc((size_t)N_EDGES * 8);
    int2*      ev     = (int2*)     alloc((size_t)N_EDGES * 8);
    int*       evc    = (int*)      alloc((size_t)N_EDGES * 4);
    __half*    hbuf   = (__half*)   alloc((size_t)N_NODES * 128 * 2);
    __half*    abuf   = (__half*)   alloc((size_t)N_NODES * 128 * 2);
    __half*    ybuf   = (__half*)   alloc((size_t)N_NODES * 40 * 2);
    _Float16*  Wt1    = (_Float16*) alloc((size_t)128 * 128 * 2);
    _Float16*  Wt2    = (_Float16*) alloc((size_t)128 * 128 * 2);
    _Float16*  Wt3    = (_Float16*) alloc((size_t)48 * 128 * 2);

    int gN = (N_NODES + 255) / 256;
    constexpr int GA   = (N_NODES + 3) / 4;        // 12500 (agg40)
    constexpr int GAS  = ((N_NODES + 15) / 16) * 4; // 12500 (sliced agg128)

    wconv_k<<<152, 256, 0, stream>>>(W1, W2, W3, Wt1, Wt2, Wt3);
    // fused: P1 bucket histogram + gemm1 (x @ W1 -> hbuf half, MFMA)
    gemm_mfma_k<float, 128, 8, true><<<NBLK + GBM, 256, 0, stream>>>(x, Wt1, hbuf, dst, gh);
    scan1_k<<<NBUCK, 256, 0, stream>>>(gh, total);
    scan2_k<<<1, 256, 0, stream>>>(total, bbase);
    bucket_k<<<NBLK, 256, 0, stream>>>(src, dst, ew, gh, bbase, bkt);
    final_k<<<NBUCK, 256, 0, stream>>>(bkt, bbase, ev, rowptr, dinv);
    norm_k<<<gN, 256, 0, stream>>>(ev, rowptr, dinv, evc);

    agg128s_k<<<GAS, 256, 0, stream>>>(hbuf, evc, rowptr, dinv, b1, abuf);
    gemm_mfma_k<__half, 128, 8, false><<<GBM, 256, 0, stream>>>(abuf, Wt2, hbuf, nullptr, nullptr);
    agg128s_k<<<GAS, 256, 0, stream>>>(hbuf, evc, rowptr, dinv, b2, abuf);
    gemm_mfma_k<__half, 40, 3, false><<<GBM, 256, 0, stream>>>(abuf, Wt3, ybuf, nullptr, nullptr);
    agg40_k<<<GA, 256, 0, stream>>>(ybuf, evc, rowptr, dinv, b3, out);
}

// Round 9
// 266.921 us; speedup vs baseline: 1.0455x; 1.0455x over previous
//
#include <hip/hip_runtime.h>
#include <hip/hip_fp16.h>

constexpr int N_NODES = 50000;
constexpr int N_EDGES = 640000;

constexpr int NBLK  = 256;                    // edge-chunk blocks
constexpr int EPB   = N_EDGES / NBLK;         // 2500 (exact)
constexpr int NBUCK = (N_NODES + 255) / 256;  // 196 buckets of 256 dst each
constexpr int GBM   = (N_NODES + 63) / 64;    // mfma-gemm blocks (64 rows each)

typedef _Float16 half8  __attribute__((ext_vector_type(8)));
typedef _Float16 half4v __attribute__((ext_vector_type(4)));
typedef float    floatx4 __attribute__((ext_vector_type(4)));

// ---------------- W -> W^T fp16 conversion (one-time, tiny); also zeros scan flag ----------------

__global__ void wconv_k(const float* __restrict__ W1, const float* __restrict__ W2,
                        const float* __restrict__ W3, _Float16* __restrict__ Wt1,
                        _Float16* __restrict__ Wt2, _Float16* __restrict__ Wt3,
                        int* __restrict__ flag) {
    int i = blockIdx.x * 256 + threadIdx.x;
    if (i == 0) *flag = 0;
    if (i < 16384) {
        int n = i >> 7, k = i & 127;
        Wt1[n * 128 + k] = (_Float16)W1[k * 128 + n];
    } else if (i < 32768) {
        int j = i - 16384; int n = j >> 7, k = j & 127;
        Wt2[n * 128 + k] = (_Float16)W2[k * 128 + n];
    } else if (i < 32768 + 6144) {
        int j = i - 32768; int n = j >> 7, k = j & 127;
        Wt3[n * 128 + k] = (_Float16)((n < 40) ? W3[k * 40 + n] : 0.f);
    }
}

// ---------------- MFMA GEMM: H[N,F_OUT] = X[N,128] @ W, fp16 in/out, fp32 acc ----------------

template<typename TIN, int F_OUT, int NT, bool FUSE_HIST>
__global__ __launch_bounds__(256) void gemm_mfma_k(const TIN* __restrict__ X,
        const _Float16* __restrict__ Wt, __half* __restrict__ H,
        const int* __restrict__ dst, int* __restrict__ gh) {
    if constexpr (FUSE_HIST) {
        if (blockIdx.x < NBLK) {
            __shared__ int lh[256];
            int t = threadIdx.x, b = blockIdx.x;
            lh[t] = 0;
            __syncthreads();
            int e0 = b * EPB;
            for (int j = t; j < EPB; j += 256)
                atomicAdd(&lh[dst[e0 + j] >> 8], 1);
            __syncthreads();
            if (t < NBUCK) gh[b * NBUCK + t] = lh[t];
            return;
        }
    }
    int bid = FUSE_HIST ? (int)blockIdx.x - NBLK : (int)blockIdx.x;

    __shared__ _Float16 Xs[64 * 136];      // 64 rows, stride 136 (16B-aligned pad)
    int tid = threadIdx.x;
    int row0 = bid * 64;

    if constexpr (sizeof(TIN) == 4) {      // fp32 input -> convert
        for (int idx = tid; idx < 2048; idx += 256) {
            int r = idx >> 5, c4 = idx & 31;
            float4 v = {0.f, 0.f, 0.f, 0.f};
            if (row0 + r < N_NODES)
                v = *(const float4*)((const float*)X + (size_t)(row0 + r) * 128 + c4 * 4);
            half4v h;
            h[0] = (_Float16)v.x; h[1] = (_Float16)v.y;
            h[2] = (_Float16)v.z; h[3] = (_Float16)v.w;
            *(half4v*)&Xs[r * 136 + c4 * 4] = h;
        }
    } else {                               // fp16 input -> raw copy
        for (int idx = tid; idx < 1024; idx += 256) {
            int r = idx >> 4, c8 = idx & 15;
            int4 v = {0, 0, 0, 0};
            if (row0 + r < N_NODES)
                v = *(const int4*)((const __half*)X + (size_t)(row0 + r) * 128 + c8 * 8);
            *(int4*)&Xs[r * 136 + c8 * 8] = v;
        }
    }
    __syncthreads();

    int lane = tid & 63;
    int wv   = tid >> 6;                   // wave 0..3 -> rows wv*16..+15
    int m    = lane & 15;
    int q    = lane >> 4;

    half8 af[4];
    #pragma unroll
    for (int kt = 0; kt < 4; kt++)
        af[kt] = *(const half8*)&Xs[(wv * 16 + m) * 136 + kt * 32 + q * 8];

    floatx4 acc[NT];
    #pragma unroll
    for (int nt = 0; nt < NT; nt++) { acc[nt][0] = 0.f; acc[nt][1] = 0.f; acc[nt][2] = 0.f; acc[nt][3] = 0.f; }

    #pragma unroll
    for (int nt = 0; nt < NT; nt++) {
        const _Float16* wp = Wt + (size_t)(nt * 16 + m) * 128 + q * 8;
        half8 b0 = *(const half8*)(wp);
        half8 b1 = *(const half8*)(wp + 32);
        half8 b2 = *(const half8*)(wp + 64);
        half8 b3 = *(const half8*)(wp + 96);
        acc[nt] = __builtin_amdgcn_mfma_f32_16x16x32_f16(af[0], b0, acc[nt], 0, 0, 0);
        acc[nt] = __builtin_amdgcn_mfma_f32_16x16x32_f16(af[1], b1, acc[nt], 0, 0, 0);
        acc[nt] = __builtin_amdgcn_mfma_f32_16x16x32_f16(af[2], b2, acc[nt], 0, 0, 0);
        acc[nt] = __builtin_amdgcn_mfma_f32_16x16x32_f16(af[3], b3, acc[nt], 0, 0, 0);
    }

    // C -> own wave's LDS region (rows wv*16..+15 only; no cross-wave hazard)
    #pragma unroll
    for (int nt = 0; nt < NT; nt++) {
        #pragma unroll
        for (int r = 0; r < 4; r++)
            Xs[(wv * 16 + q * 4 + r) * 136 + nt * 16 + m] = (_Float16)acc[nt][r];
    }

    // coalesced copy-out of own region
    if constexpr (F_OUT == 128) {
        for (int g = lane; g < 256; g += 64) {
            int r = g >> 4, c8 = g & 15;
            int row = row0 + wv * 16 + r;
            if (row < N_NODES)
                *(int4*)((__half*)H + (size_t)row * 128 + c8 * 8) =
                    *(const int4*)&Xs[(wv * 16 + r) * 136 + c8 * 8];
        }
    } else {                               // F_OUT = 40: 5 int4 per row
        for (int g = lane; g < 80; g += 64) {
            int r = g / 5, seg = g - r * 5;
            int row = row0 + wv * 16 + r;
            if (row < N_NODES)
                *(int4*)((__half*)H + (size_t)row * 40 + seg * 8) =
                    *(const int4*)&Xs[(wv * 16 + r) * 136 + seg * 8];
        }
    }
}

// ---------------- scan1 (+ scan2 folded in via last-finisher tail block) ----------------

__global__ __launch_bounds__(256) void scan1_k(int* __restrict__ gh, int* __restrict__ total,
                                               int* __restrict__ bbase, int* __restrict__ flag) {
    __shared__ int s[256];
    __shared__ int amLast;
    int t = threadIdx.x, b = blockIdx.x;
    int v = gh[t * NBUCK + b];
    s[t] = v;
    __syncthreads();
    int x = v;
    for (int off = 1; off < 256; off <<= 1) {
        int u = (t >= off) ? s[t - off] : 0;
        __syncthreads();
        x += u; s[t] = x;
        __syncthreads();
    }
    gh[t * NBUCK + b] = x - v;            // exclusive within bucket
    if (t == 255) total[b] = x;
    __threadfence();
    if (t == 0) amLast = (atomicAdd(flag, 1) == NBUCK - 1);
    __syncthreads();
    if (!amLast) return;
    __threadfence();                      // acquire all totals
    int tv = (t < NBUCK) ? total[t] : 0;
    s[t] = tv;
    __syncthreads();
    int tx = tv;
    for (int off = 1; off < 256; off <<= 1) {
        int u = (t >= off) ? s[t - off] : 0;
        __syncthreads();
        tx += u; s[t] = tx;
        __syncthreads();
    }
    if (t <= NBUCK) bbase[t] = tx - tv;
}

// ---------------- bucket scatter (LDS cursors, no global atomics) ----------------

__global__ __launch_bounds__(256) void bucket_k(const int* __restrict__ src,
        const int* __restrict__ dst, const float* __restrict__ ew,
        const int* __restrict__ gh, const int* __restrict__ bbase,
        int2* __restrict__ bkt) {
    __shared__ int cur[256];
    int t = threadIdx.x, b = blockIdx.x;
    if (t < NBUCK) cur[t] = bbase[t] + gh[b * NBUCK + t];
    __syncthreads();
    int e0 = b * EPB;
    for (int j = t; j < EPB; j += 256) {
        int d = dst[e0 + j];
        int pos = atomicAdd(&cur[d >> 8], 1);
        bkt[pos] = make_int2(src[e0 + j] | (d << 16), __float_as_int(ew[e0 + j]));
    }
}

// ---------------- finalize: per-bucket dst sort + rowptr + dinv ----------------

__global__ __launch_bounds__(256) void final_k(const int2* __restrict__ bkt,
        const int* __restrict__ bbase, int2* __restrict__ ev,
        int* __restrict__ rowptr, float* __restrict__ dinv) {
    __shared__ int   cnt[256];
    __shared__ float wsum[256];
    __shared__ int   s[256];
    int t = threadIdx.x, b = blockIdx.x;
    int base = bbase[b], cntb = bbase[b + 1] - base;
    cnt[t] = 0; wsum[t] = 0.f;
    __syncthreads();
    for (int j = t; j < cntb; j += 256) {
        int2 r = bkt[base + j];
        int bin = (r.x >> 16) & 255;
        atomicAdd(&cnt[bin], 1);
        atomicAdd(&wsum[bin], __int_as_float(r.y));
    }
    __syncthreads();
    int v = cnt[t];
    s[t] = v;
    __syncthreads();
    int x = v;
    for (int off = 1; off < 256; off <<= 1) {
        int u = (t >= off) ? s[t - off] : 0;
        __syncthreads();
        x += u; s[t] = x;
        __syncthreads();
    }
    int off_t = x - v;
    int nd = b * 256 + t;
    if (nd < N_NODES) {
        rowptr[nd] = base + off_t;
        dinv[nd] = rsqrtf(1.0f + wsum[t]);
    }
    if (b == 0 && t == 0) rowptr[N_NODES] = N_EDGES;
    s[t] = off_t;
    __syncthreads();
    for (int j = t; j < cntb; j += 256) {
        int2 r = bkt[base + j];
        int bin = (r.x >> 16) & 255;
        int p = atomicAdd(&s[bin], 1);
        ev[base + p] = make_int2(r.x & 0xFFFF, r.y);
    }
}

// ---------------- Aggregation pass 1: ev-based, writes evc ----------------
// out_i = relu( dinv_i*( sum_e ew*dinv[src]*h[src] + dinv_i*h_i ) + bias )
// evc[e] = src16 | half(ew*dinv_s*dinv_d)<<16   (wave-uniform; lane 0 stores)

__global__ __launch_bounds__(256) void agg128_ev_k(const __half* __restrict__ H,
        const int2* __restrict__ ev, const int* __restrict__ rowptr,
        const float* __restrict__ dinv, const float* __restrict__ bias,
        __half* __restrict__ out, int* __restrict__ evc) {
    int lane = threadIdx.x & 63;
    int node = __builtin_amdgcn_readfirstlane(blockIdx.x * 4 + (threadIdx.x >> 6));
    if (node >= N_NODES) return;
    const __half2* __restrict__ H2 = (const __half2*)H;
    float di = dinv[node];
    float2 hs = __half22float2(H2[(size_t)node * 64 + lane]);
    float ax = di * hs.x, ay = di * hs.y;
    int e0 = rowptr[node], e1 = rowptr[node + 1];
    int e = e0;
    for (; e + 4 <= e1; e += 4) {
        int2 p0 = ev[e + 0];
        int2 p1 = ev[e + 1];
        int2 p2 = ev[e + 2];
        int2 p3 = ev[e + 3];
        float d0 = dinv[p0.x], d1 = dinv[p1.x], d2 = dinv[p2.x], d3 = dinv[p3.x];
        float2 g0 = __half22float2(H2[(size_t)p0.x * 64 + lane]);
        float2 g1 = __half22float2(H2[(size_t)p1.x * 64 + lane]);
        float2 g2 = __half22float2(H2[(size_t)p2.x * 64 + lane]);
        float2 g3 = __half22float2(H2[(size_t)p3.x * 64 + lane]);
        float v0 = __int_as_float(p0.y) * d0;
        float v1 = __int_as_float(p1.y) * d1;
        float v2 = __int_as_float(p2.y) * d2;
        float v3 = __int_as_float(p3.y) * d3;
        if (lane == 0) {
            evc[e + 0] = p0.x | ((int)__half_as_ushort(__float2half_rn(v0 * di)) << 16);
            evc[e + 1] = p1.x | ((int)__half_as_ushort(__float2half_rn(v1 * di)) << 16);
            evc[e + 2] = p2.x | ((int)__half_as_ushort(__float2half_rn(v2 * di)) << 16);
            evc[e + 3] = p3.x | ((int)__half_as_ushort(__float2half_rn(v3 * di)) << 16);
        }
        ax = fmaf(v0, g0.x, ax); ay = fmaf(v0, g0.y, ay);
        ax = fmaf(v1, g1.x, ax); ay = fmaf(v1, g1.y, ay);
        ax = fmaf(v2, g2.x, ax); ay = fmaf(v2, g2.y, ay);
        ax = fmaf(v3, g3.x, ax); ay = fmaf(v3, g3.y, ay);
    }
    for (; e < e1; e++) {
        int2 p = ev[e];
        float v = __int_as_float(p.y) * dinv[p.x];
        float2 g = __half22float2(H2[(size_t)p.x * 64 + lane]);
        if (lane == 0)
            evc[e] = p.x | ((int)__half_as_ushort(__float2half_rn(v * di)) << 16);
        ax = fmaf(v, g.x, ax);
        ay = fmaf(v, g.y, ay);
    }
    float2 b = *(const float2*)&bias[2 * lane];
    ax = fmaxf(fmaf(ax, di, b.x), 0.f);
    ay = fmaxf(fmaf(ay, di, b.y), 0.f);
    ((__half2*)out)[(size_t)node * 64 + lane] = __float22half2_rn(make_float2(ax, ay));
}

// ---------------- Aggregation pass 2: evc-based, 128 features ----------------
// out_i = relu( sum_e norm*h[src] + dinv_i^2*h_i + bias )

__global__ __launch_bounds__(256) void agg128_evc_k(const __half* __restrict__ H,
        const int* __restrict__ evc, const int* __restrict__ rowptr,
        const float* __restrict__ dinv, const float* __restrict__ bias,
        __half* __restrict__ out) {
    int lane = threadIdx.x & 63;
    int node = __builtin_amdgcn_readfirstlane(blockIdx.x * 4 + (threadIdx.x >> 6));
    if (node >= N_NODES) return;
    const __half2* __restrict__ H2 = (const __half2*)H;
    float di = dinv[node];
    float sn = di * di;
    float2 hs = __half22float2(H2[(size_t)node * 64 + lane]);
    float ax = sn * hs.x, ay = sn * hs.y;
    int e0 = rowptr[node], e1 = rowptr[node + 1];
    int e = e0;
    for (; e + 8 <= e1; e += 8) {
        int v[8];
        #pragma unroll
        for (int j = 0; j < 8; j++) v[j] = evc[e + j];
        float2 g[8];
        #pragma unroll
        for (int j = 0; j < 8; j++)
            g[j] = __half22float2(H2[(size_t)(v[j] & 0xFFFF) * 64 + lane]);
        #pragma unroll
        for (int j = 0; j < 8; j++) {
            float w = __half2float(__ushort_as_half((unsigned short)((unsigned)v[j] >> 16)));
            ax = fmaf(w, g[j].x, ax);
            ay = fmaf(w, g[j].y, ay);
        }
    }
    for (; e < e1; e++) {
        int v = evc[e];
        float2 gv = __half22float2(H2[(size_t)(v & 0xFFFF) * 64 + lane]);
        float w = __half2float(__ushort_as_half((unsigned short)((unsigned)v >> 16)));
        ax = fmaf(w, gv.x, ax);
        ay = fmaf(w, gv.y, ay);
    }
    float2 b = *(const float2*)&bias[2 * lane];
    ax = fmaxf(ax + b.x, 0.f);
    ay = fmaxf(ay + b.y, 0.f);
    ((__half2*)out)[(size_t)node * 64 + lane] = __float22half2_rn(make_float2(ax, ay));
}

// ---------------- Aggregation, 40 features -> fp32 out with bias ----------------

__global__ __launch_bounds__(256) void agg40_k(const __half* __restrict__ Y,
        const int* __restrict__ evc, const int* __restrict__ rowptr,
        const float* __restrict__ dinv, const float* __restrict__ bias,
        float* __restrict__ out) {
    int lane = threadIdx.x & 63;
    int node = __builtin_amdgcn_readfirstlane(blockIdx.x * 4 + (threadIdx.x >> 6));
    if (node >= N_NODES) return;
    const __half2* __restrict__ Y2 = (const __half2*)Y;
    int f = (lane < 20) ? lane : 0;            // half2 column
    float di = dinv[node];
    float sn = di * di;
    float2 ys = __half22float2(Y2[(size_t)node * 20 + f]);
    float ax = sn * ys.x, ay = sn * ys.y;
    int e0 = rowptr[node], e1 = rowptr[node + 1];
    int e = e0;
    for (; e + 8 <= e1; e += 8) {
        int v[8];
        #pragma unroll
        for (int j = 0; j < 8; j++) v[j] = evc[e + j];
        float2 g[8];
        #pragma unroll
        for (int j = 0; j < 8; j++)
            g[j] = __half22float2(Y2[(size_t)(v[j] & 0xFFFF) * 20 + f]);
        #pragma unroll
        for (int j = 0; j < 8; j++) {
            float w = __half2float(__ushort_as_half((unsigned short)((unsigned)v[j] >> 16)));
            ax = fmaf(w, g[j].x, ax);
            ay = fmaf(w, g[j].y, ay);
        }
    }
    for (; e < e1; e++) {
        int v = evc[e];
        float2 gv = __half22float2(Y2[(size_t)(v & 0xFFFF) * 20 + f]);
        float w = __half2float(__ushort_as_half((unsigned short)((unsigned)v >> 16)));
        ax = fmaf(w, gv.x, ax);
        ay = fmaf(w, gv.y, ay);
    }
    if (lane < 20) {
        float2 b = *(const float2*)&bias[2 * lane];
        float2 o;
        o.x = ax + b.x;
        o.y = ay + b.y;
        *(float2*)&out[(size_t)node * 40 + 2 * lane] = o;
    }
}

// ---------------- launch ----------------

extern "C" void kernel_launch(void* const* d_in, const int* in_sizes, int n_in,
                              void* d_out, int out_size, void* d_ws, size_t ws_size,
                              hipStream_t stream) {
    const float* x  = (const float*)d_in[0];
    const int*   ei = (const int*)d_in[1];
    const int*   src = ei;
    const int*   dst = ei + N_EDGES;
    const float* ew = (const float*)d_in[2];
    const float* W1 = (const float*)d_in[3];
    const float* b1 = (const float*)d_in[4];
    const float* W2 = (const float*)d_in[5];
    const float* b2 = (const float*)d_in[6];
    const float* W3 = (const float*)d_in[7];
    const float* b3 = (const float*)d_in[8];
    float* out = (float*)d_out;

    char* w = (char*)d_ws;
    auto alloc = [&](size_t bytes) {
        char* p = w;
        w += (bytes + 255) & ~(size_t)255;
        return p;
    };
    float*     dinv   = (float*)    alloc((size_t)N_NODES * 4);
    int*       rowptr = (int*)      alloc((size_t)(N_NODES + 1) * 4);
    int*       gh     = (int*)      alloc((size_t)NBLK * NBUCK * 4);
    int*       total  = (int*)      alloc((size_t)NBUCK * 4);
    int*       bbase  = (int*)      alloc((size_t)(NBUCK + 1) * 4);
    int*       flag   = (int*)      alloc(256);
    int2*      bkt    = (int2*)     alloc((size_t)N_EDGES * 8);
    int2*      ev     = (int2*)     alloc((size_t)N_EDGES * 8);
    int*       evc    = (int*)      alloc((size_t)N_EDGES * 4);
    __half*    hbuf   = (__half*)   alloc((size_t)N_NODES * 128 * 2);
    __half*    abuf   = (__half*)   alloc((size_t)N_NODES * 128 * 2);
    __half*    ybuf   = (__half*)   alloc((size_t)N_NODES * 40 * 2);
    _Float16*  Wt1    = (_Float16*) alloc((size_t)128 * 128 * 2);
    _Float16*  Wt2    = (_Float16*) alloc((size_t)128 * 128 * 2);
    _Float16*  Wt3    = (_Float16*) alloc((size_t)48 * 128 * 2);

    constexpr int GA = (N_NODES + 3) / 4;      // 12500

    wconv_k<<<152, 256, 0, stream>>>(W1, W2, W3, Wt1, Wt2, Wt3, flag);
    // fused: P1 bucket histogram + gemm1 (x @ W1 -> hbuf half, MFMA)
    gemm_mfma_k<float, 128, 8, true><<<NBLK + GBM, 256, 0, stream>>>(x, Wt1, hbuf, dst, gh);
    scan1_k<<<NBUCK, 256, 0, stream>>>(gh, total, bbase, flag);
    bucket_k<<<NBLK, 256, 0, stream>>>(src, dst, ew, gh, bbase, bkt);
    final_k<<<NBUCK, 256, 0, stream>>>(bkt, bbase, ev, rowptr, dinv);

    agg128_ev_k<<<GA, 256, 0, stream>>>(hbuf, ev, rowptr, dinv, b1, abuf, evc);
    gemm_mfma_k<__half, 128, 8, false><<<GBM, 256, 0, stream>>>(abuf, Wt2, hbuf, nullptr, nullptr);
    agg128_evc_k<<<GA, 256, 0, stream>>>(hbuf, evc, rowptr, dinv, b2, abuf);
    gemm_mfma_k<__half, 40, 3, false><<<GBM, 256, 0, stream>>>(abuf, Wt3, ybuf, nullptr, nullptr);
    agg40_k<<<GA, 256, 0, stream>>>(ybuf, evc, rowptr, dinv, b3, out);
}